// Round 1
// baseline (268.161 us; speedup 1.0000x reference)
//
#include <hip/hip_runtime.h>
#include <hip/hip_bf16.h>
#include <stdint.h>

#define NN 4096
#define KIN 512
#define HH 8
#define FF 32
#define HF 256

typedef float f32x4 __attribute__((ext_vector_type(4)));
typedef short s16x8 __attribute__((ext_vector_type(8)));
typedef __bf16 bf16x8 __attribute__((ext_vector_type(8)));

#define LOG2E 1.4426950408889634f

// ---------------------------------------------------------------------------
// Kernel A (prep): x = node@W (fp32, 64x64 tiles), emits:
//   - XT   : x transposed as bf16, [256][4096]  (B-operand friendly)
//   - sSrcT: [8][4096] = (x . a[:32])  * log2(e)
//   - sTgtT: [8][4096] = (x . a[32:])  * log2(e)
//   - flag : adjacency storage mode sniffed from first 64 words
// ---------------------------------------------------------------------------
__global__ __launch_bounds__(256) void k_prep(
    const float* __restrict__ node, const float* __restrict__ Wm,
    const float* __restrict__ avec, const void* __restrict__ adjv,
    __hip_bfloat16* __restrict__ XT, float* __restrict__ sSrcT,
    float* __restrict__ sTgtT, int* __restrict__ flag) {
  // --- adjacency dtype detection (adj[0][0]==1 guaranteed by self-loop) ---
  if (blockIdx.x == 0 && blockIdx.y == 0 && threadIdx.x == 0) {
    const uint32_t* aw = (const uint32_t*)adjv;
    const uint32_t w0 = aw[0];
    int f;
    if (w0 == 0x3F800000u) {
      f = 2;                                   // fp32 0.0/1.0
    } else if ((w0 & 0xFFFFu) == 0x3F80u) {
      f = 3;                                   // bf16 0/1
    } else {
      int alli = 1;
      for (int k = 0; k < 64; ++k) {
        if (aw[k] > 1u) { alli = 0; break; }
      }
      f = alli ? 1 : 0;                        // int32 0/1 : uint8 bool
    }
    *flag = f;
  }

  __shared__ float As[16][68];   // [k][row], padded, 16B-aligned rows
  __shared__ float Bs[16][68];   // [k][col]
  const int tid = threadIdx.x;
  const int row0 = blockIdx.x * 64;
  const int col0 = blockIdx.y * 64;
  const int tx = tid & 15, ty = tid >> 4;

  float acc[4][4] = {};
  for (int k0 = 0; k0 < KIN; k0 += 16) {
    {
      const int r = tid >> 2, kk = (tid & 3) * 4;
      const float4 av = *(const float4*)(node + (size_t)(row0 + r) * KIN + k0 + kk);
      As[kk + 0][r] = av.x; As[kk + 1][r] = av.y;
      As[kk + 2][r] = av.z; As[kk + 3][r] = av.w;
    }
    {
      const int kk = tid >> 4, c = (tid & 15) * 4;
      *(float4*)(&Bs[kk][c]) = *(const float4*)(Wm + (size_t)(k0 + kk) * HF + col0 + c);
    }
    __syncthreads();
#pragma unroll
    for (int kk = 0; kk < 16; ++kk) {
      const float4 a4 = *(const float4*)(&As[kk][ty * 4]);
      const float4 b4 = *(const float4*)(&Bs[kk][tx * 4]);
      const float aa[4] = {a4.x, a4.y, a4.z, a4.w};
      const float bb[4] = {b4.x, b4.y, b4.z, b4.w};
#pragma unroll
      for (int r = 0; r < 4; ++r)
#pragma unroll
        for (int c = 0; c < 4; ++c)
          acc[r][c] = fmaf(aa[r], bb[c], acc[r][c]);
    }
    __syncthreads();
  }

  // --- s_src / s_tgt partial dots; 64 cols of this tile = heads 2*bj, 2*bj+1
  float as_[4], at_[4];
#pragma unroll
  for (int c = 0; c < 4; ++c) {
    const int f = (tx * 4 + c) & 31;
    as_[c] = avec[f] * LOG2E;
    at_[c] = avec[32 + f] * LOG2E;
  }
  float ps[4] = {0, 0, 0, 0}, pt[4] = {0, 0, 0, 0};
#pragma unroll
  for (int r = 0; r < 4; ++r)
#pragma unroll
    for (int c = 0; c < 4; ++c) {
      ps[r] = fmaf(acc[r][c], as_[c], ps[r]);
      pt[r] = fmaf(acc[r][c], at_[c], pt[r]);
    }
  // reduce across the 8 threads (tx bits 0..2) holding one (row, head)
#pragma unroll
  for (int m = 1; m <= 4; m <<= 1) {
#pragma unroll
    for (int r = 0; r < 4; ++r) {
      ps[r] += __shfl_xor(ps[r], m);
      pt[r] += __shfl_xor(pt[r], m);
    }
  }
  if ((tx & 7) == 0) {
    const int h = blockIdx.y * 2 + (tx >> 3);
#pragma unroll
    for (int r = 0; r < 4; ++r) {
      sSrcT[h * NN + row0 + ty * 4 + r] = ps[r];
      sTgtT[h * NN + row0 + ty * 4 + r] = pt[r];
    }
  }

  // --- scatter x^T as bf16 (total 2 MB, L2-absorbed) ---
#pragma unroll
  for (int r = 0; r < 4; ++r)
#pragma unroll
    for (int c = 0; c < 4; ++c) {
      XT[(size_t)(col0 + tx * 4 + c) * NN + row0 + ty * 4 + r] =
          __float2bfloat16(acc[r][c]);
    }
}

// ---------------------------------------------------------------------------
// Kernel B (attention): one wave per (16-target tile, head).
// P generated per-lane in MFMA A-layout (A[m=lane&15][k=quad*8+j]);
// B-frags are 16B loads from XT; C/D layout col=lane&15, row=quad*4+reg.
// ---------------------------------------------------------------------------
__global__ __launch_bounds__(256) void k_attn(
    const void* __restrict__ adjv, const int* __restrict__ flagp,
    const __hip_bfloat16* __restrict__ XT, const float* __restrict__ sSrcT,
    const float* __restrict__ sTgtT, float* __restrict__ out) {
  const int wave = threadIdx.x >> 6;
  const int lane = threadIdx.x & 63;
  const int pair = blockIdx.x * 4 + wave;  // 0..2047
  const int tile = pair >> 3;              // 0..255
  const int h = pair & 7;
  const int nl = lane & 15;
  const int quad = lane >> 4;
  const int i0 = tile * 16;
  const int mode = *flagp;

  const float tlog = sTgtT[h * NN + i0 + nl];  // t' for A-row m = nl
  const float* srow = sSrcT + h * NN;
  const uint16_t* x0 = (const uint16_t*)XT + (size_t)(h * 32 + nl) * NN;
  const uint16_t* x1 = x0 + (size_t)16 * NN;

  f32x4 acc0 = {0.f, 0.f, 0.f, 0.f}, acc1 = {0.f, 0.f, 0.f, 0.f};
  float den = 0.f;
  const int jo = quad * 8;
  const size_t arow = (size_t)(i0 + nl);

  for (int jc = 0; jc < NN; jc += 32) {
    const int j8 = jc + jo;
    const f32x4 s0 = *(const f32x4*)(srow + j8);
    const f32x4 s1 = *(const f32x4*)(srow + j8 + 4);

    float mk[8];
    if (mode == 0) {            // uint8 bool
      const uint32_t* ap = (const uint32_t*)((const uint8_t*)adjv + arow * NN + j8);
      const uint32_t b0 = ap[0], b1 = ap[1];
#pragma unroll
      for (int c = 0; c < 4; ++c) {
        mk[c]     = ((b0 >> (8 * c)) & 0xFFu) ? 1.0f : 0.0f;
        mk[c + 4] = ((b1 >> (8 * c)) & 0xFFu) ? 1.0f : 0.0f;
      }
    } else if (mode == 1) {     // int32
      const int* ap = (const int*)adjv + arow * NN + j8;
#pragma unroll
      for (int c = 0; c < 8; ++c) mk[c] = ap[c] ? 1.0f : 0.0f;
    } else if (mode == 2) {     // fp32 0/1
      const float* ap = (const float*)adjv + arow * NN + j8;
#pragma unroll
      for (int c = 0; c < 8; ++c) mk[c] = ap[c];
    } else {                    // bf16 0/1
      const uint16_t* ap = (const uint16_t*)adjv + arow * NN + j8;
#pragma unroll
      for (int c = 0; c < 8; ++c) mk[c] = ap[c] ? 1.0f : 0.0f;
    }

    const s16x8 bx0 = *(const s16x8*)(x0 + j8);
    const s16x8 bx1 = *(const s16x8*)(x1 + j8);

    union { bf16x8 b; s16x8 s; } af;
#pragma unroll
    for (int c = 0; c < 8; ++c) {
      const float sc = (c < 4) ? s0[c] : s1[c - 4];
      const float v = tlog + sc;            // already in log2 domain
      const float w = fmaxf(v, 0.2f * v);   // leaky-relu commutes with *log2e
      const float p = exp2f(w) * mk[c];
      den += p;
      af.b[c] = (__bf16)p;
    }

    acc0 = __builtin_amdgcn_mfma_f32_16x16x32_bf16(af.s, bx0, acc0, 0, 0, 0);
    acc1 = __builtin_amdgcn_mfma_f32_16x16x32_bf16(af.s, bx1, acc1, 0, 0, 0);
  }

  // den partials: lane covers (ti=nl, j in its quad's octets); reduce quads
  den += __shfl_xor(den, 16);
  den += __shfl_xor(den, 32);

#pragma unroll
  for (int r = 0; r < 4; ++r) {
    const int row_l = quad * 4 + r;               // C/D row = quad*4+reg
    const float dr = __shfl(den, row_l);          // den lives at lane&15==row_l
    const float inv = 1.0f / dr;
    const int row = i0 + row_l;
    out[(size_t)row * HF + h * 32 + nl]      = acc0[r] * inv;
    out[(size_t)row * HF + h * 32 + 16 + nl] = acc1[r] * inv;
  }
}

// ---------------------------------------------------------------------------
extern "C" void kernel_launch(void* const* d_in, const int* in_sizes, int n_in,
                              void* d_out, int out_size, void* d_ws, size_t ws_size,
                              hipStream_t stream) {
  const float* node = (const float*)d_in[0];
  const void* adj = d_in[1];
  const float* Wm = (const float*)d_in[2];
  const float* avec = (const float*)d_in[3];
  float* out = (float*)d_out;

  uint8_t* ws = (uint8_t*)d_ws;
  __hip_bfloat16* XT = (__hip_bfloat16*)ws;                       // 2 MB
  float* sSrcT = (float*)(ws + (size_t)(2u << 20));               // 128 KB
  float* sTgtT = (float*)(ws + (size_t)(2u << 20) + (128u << 10));
  int* flag = (int*)(ws + (size_t)(2u << 20) + (256u << 10));

  hipLaunchKernelGGL(k_prep, dim3(64, 4), dim3(256), 0, stream,
                     node, Wm, avec, adj, XT, sSrcT, sTgtT, flag);
  hipLaunchKernelGGL(k_attn, dim3(512), dim3(256), 0, stream,
                     adj, flag, XT, sSrcT, sTgtT, out);
}

// Round 2
// 193.096 us; speedup vs baseline: 1.3887x; 1.3887x over previous
//
#include <hip/hip_runtime.h>
#include <hip/hip_bf16.h>
#include <stdint.h>

#define NN 4096
#define KIN 512
#define HH 8
#define HF 256
#define LOG2E 1.4426950408889634f

typedef float f32x4 __attribute__((ext_vector_type(4)));
typedef short s16x8 __attribute__((ext_vector_type(8)));
typedef __bf16 bf16x8 __attribute__((ext_vector_type(8)));

// ---------------------------------------------------------------------------
// k_prep: x = node@W via bf16 MFMA (64x64 tiles). Emits XT (bf16 [256][4096]),
// sSrcT/sTgtT ([8][4096], log2-domain), and adjacency-mode flag.
// ---------------------------------------------------------------------------
__global__ __launch_bounds__(256) void k_prep(
    const float* __restrict__ node, const float* __restrict__ Wm,
    const float* __restrict__ avec, const void* __restrict__ adjv,
    __hip_bfloat16* __restrict__ XT, float* __restrict__ sSrcT,
    float* __restrict__ sTgtT, int* __restrict__ flag) {
  if (blockIdx.x == 0 && blockIdx.y == 0 && threadIdx.x == 0) {
    const uint32_t* aw = (const uint32_t*)adjv;
    const uint32_t w0 = aw[0];
    int f;
    if (w0 == 0x3F800000u) f = 2;                 // fp32 0/1
    else if ((w0 & 0xFFFFu) == 0x3F80u) f = 3;    // bf16 0/1
    else {
      int alli = 1;
      for (int k = 0; k < 64; ++k)
        if (aw[k] > 1u) { alli = 0; break; }
      f = alli ? 1 : 0;                           // int32 : uint8
    }
    *flag = f;
  }

  __shared__ __hip_bfloat16 Ald[64][40];  // stride 40 elems (80B): 2-way free
  __shared__ __hip_bfloat16 Bld[64][40];  // [col][k]
  const int tid = threadIdx.x;
  const int wv = tid >> 6, ln = tid & 63, nl = ln & 15, qd = ln >> 4;
  const int row0 = blockIdx.x * 64, col0 = blockIdx.y * 64;
  const int rA = tid >> 2, kA = (tid & 3) * 8;    // A stage: 64 rows x 32 k
  const int kB = tid >> 3, cB = (tid & 7) * 8;    // B stage: 32 k x 64 cols

  f32x4 acc[4] = {{0,0,0,0},{0,0,0,0},{0,0,0,0},{0,0,0,0}};

  for (int k0 = 0; k0 < KIN; k0 += 32) {
    const float4 a0 = *(const float4*)(node + (size_t)(row0 + rA) * KIN + k0 + kA);
    const float4 a1 = *(const float4*)(node + (size_t)(row0 + rA) * KIN + k0 + kA + 4);
    const float4 b0 = *(const float4*)(Wm + (size_t)(k0 + kB) * HF + col0 + cB);
    const float4 b1 = *(const float4*)(Wm + (size_t)(k0 + kB) * HF + col0 + cB + 4);
    __syncthreads();
    {
      union { bf16x8 v; s16x8 s; } pk;
      pk.v[0] = (__bf16)a0.x; pk.v[1] = (__bf16)a0.y;
      pk.v[2] = (__bf16)a0.z; pk.v[3] = (__bf16)a0.w;
      pk.v[4] = (__bf16)a1.x; pk.v[5] = (__bf16)a1.y;
      pk.v[6] = (__bf16)a1.z; pk.v[7] = (__bf16)a1.w;
      *(s16x8*)&Ald[rA][kA] = pk.s;
      Bld[cB + 0][kB] = __float2bfloat16(b0.x);
      Bld[cB + 1][kB] = __float2bfloat16(b0.y);
      Bld[cB + 2][kB] = __float2bfloat16(b0.z);
      Bld[cB + 3][kB] = __float2bfloat16(b0.w);
      Bld[cB + 4][kB] = __float2bfloat16(b1.x);
      Bld[cB + 5][kB] = __float2bfloat16(b1.y);
      Bld[cB + 6][kB] = __float2bfloat16(b1.z);
      Bld[cB + 7][kB] = __float2bfloat16(b1.w);
    }
    __syncthreads();
    const s16x8 af = *(const s16x8*)&Ald[wv * 16 + nl][qd * 8];
#pragma unroll
    for (int ct = 0; ct < 4; ++ct) {
      const s16x8 bfr = *(const s16x8*)&Bld[ct * 16 + nl][qd * 8];
      acc[ct] = __builtin_amdgcn_mfma_f32_16x16x32_bf16(af, bfr, acc[ct], 0, 0, 0);
    }
  }

  // XT[col][row] scatter
#pragma unroll
  for (int ct = 0; ct < 4; ++ct)
#pragma unroll
    for (int r = 0; r < 4; ++r)
      XT[(size_t)(col0 + ct * 16 + nl) * NN + row0 + wv * 16 + qd * 4 + r] =
          __float2bfloat16(acc[ct][r]);

  // s_src / s_tgt (log2-domain). This wave's cols cover heads by*2, by*2+1.
  const float as0 = avec[nl] * LOG2E, as1 = avec[16 + nl] * LOG2E;
  const float at0 = avec[32 + nl] * LOG2E, at1 = avec[48 + nl] * LOG2E;
#pragma unroll
  for (int hp = 0; hp < 2; ++hp) {
    float ps[4], pt[4];
#pragma unroll
    for (int r = 0; r < 4; ++r) {
      ps[r] = acc[2 * hp][r] * as0 + acc[2 * hp + 1][r] * as1;
      pt[r] = acc[2 * hp][r] * at0 + acc[2 * hp + 1][r] * at1;
    }
#pragma unroll
    for (int m = 1; m <= 8; m <<= 1)
#pragma unroll
      for (int r = 0; r < 4; ++r) {
        ps[r] += __shfl_xor(ps[r], m);
        pt[r] += __shfl_xor(pt[r], m);
      }
    if (nl == 0) {
      const int h = blockIdx.y * 2 + hp;
#pragma unroll
      for (int r = 0; r < 4; ++r) {
        sSrcT[h * NN + row0 + wv * 16 + qd * 4 + r] = ps[r];
        sTgtT[h * NN + row0 + wv * 16 + qd * 4 + r] = pt[r];
      }
    }
  }
}

// ---------------------------------------------------------------------------
// k_attn: block = 16 target rows x ALL 8 heads (8 waves). Adjacency chunk
// (16x256) loaded coalesced, decoded once, staged as float in LDS (shared by
// 8 heads). gridDim.y = j-split; partials to ws unless JS==1.
// ---------------------------------------------------------------------------
__global__ __launch_bounds__(512) void k_attn(
    const void* __restrict__ adjv, const int* __restrict__ flagp,
    const __hip_bfloat16* __restrict__ XT, const float* __restrict__ sSrcT,
    const float* __restrict__ sTgtT, __hip_bfloat16* __restrict__ pnum,
    float* __restrict__ pden, float* __restrict__ out) {
  __shared__ float Msk[16][260];  // stride 260 words: 16B-aligned, 2-way free
  const int h = threadIdx.x >> 6;
  const int ln = threadIdx.x & 63, nl = ln & 15, qd = ln >> 4;
  const int tile = blockIdx.x, js = blockIdx.y, JS = gridDim.y;
  const int i0 = tile * 16;
  const int jlen = NN / JS, j0 = js * jlen, NC = jlen / 256;
  const int mode = *flagp;
  const int strow = threadIdx.x >> 5, stcol = (threadIdx.x & 31) * 8;

  const float tlog = sTgtT[h * NN + i0 + nl];
  const float* sS = sSrcT + h * NN;
  const uint16_t* x0 = (const uint16_t*)XT + (size_t)(h * 32 + nl) * NN;
  const uint16_t* x1 = x0 + (size_t)16 * NN;

  f32x4 acc0 = {0,0,0,0}, acc1 = {0,0,0,0};
  float den = 0.f;
  float pre[8];

  auto loadRegs = [&](int jbase) {
    const size_t roff = (size_t)(i0 + strow) * NN + jbase + stcol;
    if (mode == 1) {
      const int* ap = (const int*)adjv + roff;
#pragma unroll
      for (int c = 0; c < 8; ++c) pre[c] = ap[c] ? 1.f : 0.f;
    } else if (mode == 0) {
      const uint8_t* ap = (const uint8_t*)adjv + roff;
#pragma unroll
      for (int c = 0; c < 8; ++c) pre[c] = ap[c] ? 1.f : 0.f;
    } else if (mode == 2) {
      const float* ap = (const float*)adjv + roff;
#pragma unroll
      for (int c = 0; c < 8; ++c) pre[c] = ap[c];
    } else {
      const uint16_t* ap = (const uint16_t*)adjv + roff;
#pragma unroll
      for (int c = 0; c < 8; ++c) pre[c] = ap[c] ? 1.f : 0.f;
    }
  };

  loadRegs(j0);
  for (int c = 0; c < NC; ++c) {
    __syncthreads();
    *(float4*)&Msk[strow][stcol] = (float4){pre[0], pre[1], pre[2], pre[3]};
    *(float4*)&Msk[strow][stcol + 4] = (float4){pre[4], pre[5], pre[6], pre[7]};
    __syncthreads();
    if (c + 1 < NC) loadRegs(j0 + (c + 1) * 256);

    const int jb = j0 + c * 256;
#pragma unroll
    for (int st = 0; st < 8; ++st) {
      const int jq = st * 32 + qd * 8;
      const f32x4 s0 = *(const f32x4*)(sS + jb + jq);
      const f32x4 s1 = *(const f32x4*)(sS + jb + jq + 4);
      const float4 m0 = *(const float4*)&Msk[nl][jq];
      const float4 m1 = *(const float4*)&Msk[nl][jq + 4];
      const s16x8 bx0 = *(const s16x8*)(x0 + jb + jq);
      const s16x8 bx1 = *(const s16x8*)(x1 + jb + jq);
      const float mm[8] = {m0.x, m0.y, m0.z, m0.w, m1.x, m1.y, m1.z, m1.w};
      const float ss[8] = {s0[0], s0[1], s0[2], s0[3], s1[0], s1[1], s1[2], s1[3]};
      union { bf16x8 b; s16x8 s; } af;
#pragma unroll
      for (int cc = 0; cc < 8; ++cc) {
        const float v = tlog + ss[cc];
        const float w = fmaxf(v, 0.2f * v);
        const float p = exp2f(w) * mm[cc];
        den += p;
        af.b[cc] = (__bf16)p;
      }
      acc0 = __builtin_amdgcn_mfma_f32_16x16x32_bf16(af.s, bx0, acc0, 0, 0, 0);
      acc1 = __builtin_amdgcn_mfma_f32_16x16x32_bf16(af.s, bx1, acc1, 0, 0, 0);
    }
  }

  den += __shfl_xor(den, 16);
  den += __shfl_xor(den, 32);  // lane (nl,*) now holds full den for row nl

  if (JS == 1) {
#pragma unroll
    for (int r = 0; r < 4; ++r) {
      const int rw = qd * 4 + r;
      const float inv = 1.0f / __shfl(den, rw);
      out[(size_t)(i0 + rw) * HF + h * 32 + nl] = acc0[r] * inv;
      out[(size_t)(i0 + rw) * HF + h * 32 + 16 + nl] = acc1[r] * inv;
    }
  } else {
    const size_t pb = (((size_t)js * 256 + tile) * HH + h) * 2;
#pragma unroll
    for (int r = 0; r < 4; ++r) {
      const int rw = qd * 4 + r;
      pnum[(pb * 16 + rw) * 16 + nl] = __float2bfloat16(acc0[r]);
      pnum[((pb + 1) * 16 + rw) * 16 + nl] = __float2bfloat16(acc1[r]);
    }
    if (ln < 16) pden[((size_t)js * 256 + tile) * 128 + h * 16 + ln] = den;
  }
}

// ---------------------------------------------------------------------------
__global__ __launch_bounds__(256) void k_reduce(
    const __hip_bfloat16* __restrict__ pnum, const float* __restrict__ pden,
    float* __restrict__ out, int JS) {
  const int gid = blockIdx.x * 256 + threadIdx.x;
  const int i = gid >> 8, col = gid & 255;
  const int tile = i >> 4, r = i & 15;
  const int h = col >> 5, ct = (col >> 4) & 1, cc = col & 15;
  float num = 0.f, den = 0.f;
  for (int js = 0; js < JS; ++js) {
    num += __bfloat162float(
        pnum[(((((size_t)js * 256 + tile) * 8 + h) * 2 + ct) * 16 + r) * 16 + cc]);
    den += pden[((size_t)js * 256 + tile) * 128 + h * 16 + r];
  }
  out[gid] = num / den;
}

// ---------------------------------------------------------------------------
extern "C" void kernel_launch(void* const* d_in, const int* in_sizes, int n_in,
                              void* d_out, int out_size, void* d_ws, size_t ws_size,
                              hipStream_t stream) {
  const float* node = (const float*)d_in[0];
  const void* adj = d_in[1];
  const float* Wm = (const float*)d_in[2];
  const float* avec = (const float*)d_in[3];
  float* out = (float*)d_out;

  uint8_t* ws = (uint8_t*)d_ws;
  __hip_bfloat16* XT = (__hip_bfloat16*)ws;            // 2 MB
  float* sSrcT = (float*)(ws + 0x200000);              // 128 KB
  float* sTgtT = (float*)(ws + 0x220000);              // 128 KB
  int* flag = (int*)(ws + 0x240000);                   // 4 B (pad 1 KB)
  const size_t base = 0x240400;
  int JS = 1;
  if (ws_size >= base + 4 * (2097152ull + 131072ull)) JS = 4;
  else if (ws_size >= base + 2 * (2097152ull + 131072ull)) JS = 2;
  __hip_bfloat16* pnum = (__hip_bfloat16*)(ws + base);
  float* pden = (float*)(ws + base + (size_t)JS * 2097152ull);

  hipLaunchKernelGGL(k_prep, dim3(64, 4), dim3(256), 0, stream,
                     node, Wm, avec, adj, XT, sSrcT, sTgtT, flag);
  hipLaunchKernelGGL(k_attn, dim3(256, JS), dim3(512), 0, stream,
                     adj, flag, XT, sSrcT, sTgtT, pnum, pden, out);
  if (JS > 1)
    hipLaunchKernelGGL(k_reduce, dim3(4096), dim3(256), 0, stream,
                       pnum, pden, out, JS);
}

// Round 3
// 192.633 us; speedup vs baseline: 1.3921x; 1.0024x over previous
//
#include <hip/hip_runtime.h>
#include <hip/hip_bf16.h>
#include <stdint.h>

#define NN 4096
#define KIN 512
#define HH 8
#define HF 256
#define LOG2E 1.4426950408889634f

typedef float f32x4 __attribute__((ext_vector_type(4)));
typedef short s16x8 __attribute__((ext_vector_type(8)));
typedef __bf16 bf16x8 __attribute__((ext_vector_type(8)));

#if defined(__has_builtin)
#if __has_builtin(__builtin_amdgcn_exp2f)
#define EXP2(x) __builtin_amdgcn_exp2f(x)
#else
#define EXP2(x) exp2f(x)
#endif
#else
#define EXP2(x) exp2f(x)
#endif

// ---------------------------------------------------------------------------
// k_prep: x = node@W via bf16 MFMA (64x64 tiles). Emits XT (bf16 [256][4096],
// coalesced via LDS transpose), sSrcT/sTgtT ([8][4096], log2-domain), flag.
// ---------------------------------------------------------------------------
__global__ __launch_bounds__(256) void k_prep(
    const float* __restrict__ node, const float* __restrict__ Wm,
    const float* __restrict__ avec, const void* __restrict__ adjv,
    uint16_t* __restrict__ XT, float* __restrict__ sSrcT,
    float* __restrict__ sTgtT, int* __restrict__ flag) {
  if (blockIdx.x == 0 && blockIdx.y == 0 && threadIdx.x == 0) {
    const uint32_t* aw = (const uint32_t*)adjv;
    const uint32_t w0 = aw[0];
    int f;
    if (w0 == 0x3F800000u) f = 2;                 // fp32 0/1
    else if ((w0 & 0xFFFFu) == 0x3F80u) f = 3;    // bf16 0/1
    else {
      int alli = 1;
      for (int k = 0; k < 64; ++k)
        if (aw[k] > 1u) { alli = 0; break; }
      f = alli ? 1 : 0;                           // int32 : uint8
    }
    *flag = f;
  }

  __shared__ __bf16 Ald[64][40];   // stride 80B: 16B-aligned frag rows
  __shared__ __bf16 Bld[64][40];   // [col][k]
  __shared__ __bf16 Cs[64][72];    // transpose staging, stride 144B
  const int tid = threadIdx.x;
  const int wv = tid >> 6, ln = tid & 63, nl = ln & 15, qd = ln >> 4;
  const int row0 = blockIdx.x * 64, col0 = blockIdx.y * 64;
  const int rA = tid >> 2, kA = (tid & 3) * 8;    // A stage: 64 rows x 32 k
  const int kB = tid >> 3, cB = (tid & 7) * 8;    // B stage: 32 k x 64 cols

  f32x4 acc[4] = {{0,0,0,0},{0,0,0,0},{0,0,0,0},{0,0,0,0}};
  float4 a0, a1, b0, b1;

  auto ldg = [&](int k0) {
    a0 = *(const float4*)(node + (size_t)(row0 + rA) * KIN + k0 + kA);
    a1 = *(const float4*)(node + (size_t)(row0 + rA) * KIN + k0 + kA + 4);
    b0 = *(const float4*)(Wm + (size_t)(k0 + kB) * HF + col0 + cB);
    b1 = *(const float4*)(Wm + (size_t)(k0 + kB) * HF + col0 + cB + 4);
  };

  ldg(0);
  for (int k0 = 0; k0 < KIN; k0 += 32) {
    __syncthreads();
    {
      union { bf16x8 v; s16x8 s; } pk;
      pk.v[0] = (__bf16)a0.x; pk.v[1] = (__bf16)a0.y;
      pk.v[2] = (__bf16)a0.z; pk.v[3] = (__bf16)a0.w;
      pk.v[4] = (__bf16)a1.x; pk.v[5] = (__bf16)a1.y;
      pk.v[6] = (__bf16)a1.z; pk.v[7] = (__bf16)a1.w;
      *(s16x8*)&Ald[rA][kA] = pk.s;
      Bld[cB + 0][kB] = (__bf16)b0.x;
      Bld[cB + 1][kB] = (__bf16)b0.y;
      Bld[cB + 2][kB] = (__bf16)b0.z;
      Bld[cB + 3][kB] = (__bf16)b0.w;
      Bld[cB + 4][kB] = (__bf16)b1.x;
      Bld[cB + 5][kB] = (__bf16)b1.y;
      Bld[cB + 6][kB] = (__bf16)b1.z;
      Bld[cB + 7][kB] = (__bf16)b1.w;
    }
    __syncthreads();
    if (k0 + 32 < KIN) ldg(k0 + 32);   // next slab in flight over MFMA phase
    const s16x8 af = *(const s16x8*)&Ald[wv * 16 + nl][qd * 8];
#pragma unroll
    for (int ct = 0; ct < 4; ++ct) {
      const s16x8 bfr = *(const s16x8*)&Bld[ct * 16 + nl][qd * 8];
      acc[ct] = __builtin_amdgcn_mfma_f32_16x16x32_bf16(af, bfr, acc[ct], 0, 0, 0);
    }
  }

  // --- stage C-tile in LDS (transposed), then coalesced 16B stores to XT ---
#pragma unroll
  for (int ct = 0; ct < 4; ++ct)
#pragma unroll
    for (int r = 0; r < 4; ++r)
      Cs[ct * 16 + nl][wv * 16 + qd * 4 + r] = (__bf16)acc[ct][r];
  __syncthreads();
  {
    const int xr = tid >> 2;                    // XT row within tile (= col)
#pragma unroll
    for (int sseg = 0; sseg < 2; ++sseg) {
      const int sc = ((tid & 3) * 2 + sseg) * 8;
      *(s16x8*)(XT + (size_t)(col0 + xr) * NN + row0 + sc) =
          *(const s16x8*)&Cs[xr][sc];
    }
  }

  // --- s_src / s_tgt (log2-domain); this block's cols = heads by*2, by*2+1
  const float as0 = avec[nl] * LOG2E, as1 = avec[16 + nl] * LOG2E;
  const float at0 = avec[32 + nl] * LOG2E, at1 = avec[48 + nl] * LOG2E;
#pragma unroll
  for (int hp = 0; hp < 2; ++hp) {
    float ps[4], pt[4];
#pragma unroll
    for (int r = 0; r < 4; ++r) {
      ps[r] = acc[2 * hp][r] * as0 + acc[2 * hp + 1][r] * as1;
      pt[r] = acc[2 * hp][r] * at0 + acc[2 * hp + 1][r] * at1;
    }
#pragma unroll
    for (int m = 1; m <= 8; m <<= 1)
#pragma unroll
      for (int r = 0; r < 4; ++r) {
        ps[r] += __shfl_xor(ps[r], m);
        pt[r] += __shfl_xor(pt[r], m);
      }
    if (nl == 0) {
      const int h = blockIdx.y * 2 + hp;
#pragma unroll
      for (int r = 0; r < 4; ++r) {
        sSrcT[h * NN + row0 + wv * 16 + qd * 4 + r] = ps[r];
        sTgtT[h * NN + row0 + wv * 16 + qd * 4 + r] = pt[r];
      }
    }
  }
}

// ---------------------------------------------------------------------------
// k_attn: block = 16 target rows x 8 heads (8 waves). Adjacency chunk
// (16x256) decoded once to 0xFFFF/0 uint16 in LDS; mask applied as bitwise
// AND on packed bf16 P. den via ones-MFMA (free col-broadcast).
// ---------------------------------------------------------------------------
__global__ __launch_bounds__(512) void k_attn(
    const void* __restrict__ adjv, const int* __restrict__ flagp,
    const uint16_t* __restrict__ XT, const float* __restrict__ sSrcT,
    const float* __restrict__ sTgtT, uint16_t* __restrict__ pnum,
    float* __restrict__ pden, float* __restrict__ out) {
  __shared__ uint16_t Msk[16][264];  // 528B rows: 16B-aligned
  const int h = threadIdx.x >> 6;
  const int ln = threadIdx.x & 63, nl = ln & 15, qd = ln >> 4;
  const int tile = blockIdx.x, js = blockIdx.y, JS = gridDim.y;
  const int i0 = tile * 16;
  const int jlen = NN / JS, j0 = js * jlen, NC = jlen / 256;
  const int mode = *flagp;
  const int strow = threadIdx.x >> 5, stcol = (threadIdx.x & 31) * 8;

  const float tlog = sTgtT[h * NN + i0 + nl];
  const float* sS = sSrcT + h * NN;
  const uint16_t* x0 = XT + (size_t)(h * 32 + nl) * NN;
  const uint16_t* x1 = x0 + (size_t)16 * NN;

  const short one_bf = (short)0x3F80;
  const s16x8 ONES = {one_bf, one_bf, one_bf, one_bf,
                      one_bf, one_bf, one_bf, one_bf};

  f32x4 acc0 = {0,0,0,0}, acc1 = {0,0,0,0}, accD = {0,0,0,0};
  uint16_t pre[8];

  auto loadRegs = [&](int jbase) {
    const size_t roff = (size_t)(i0 + strow) * NN + jbase + stcol;
    if (mode == 1) {
      const int* ap = (const int*)adjv + roff;
#pragma unroll
      for (int c = 0; c < 8; ++c) pre[c] = ap[c] ? 0xFFFFu : 0u;
    } else if (mode == 0) {
      const uint8_t* ap = (const uint8_t*)adjv + roff;
#pragma unroll
      for (int c = 0; c < 8; ++c) pre[c] = ap[c] ? 0xFFFFu : 0u;
    } else if (mode == 2) {
      const float* ap = (const float*)adjv + roff;
#pragma unroll
      for (int c = 0; c < 8; ++c) pre[c] = (ap[c] != 0.f) ? 0xFFFFu : 0u;
    } else {
      const uint16_t* ap = (const uint16_t*)adjv + roff;
#pragma unroll
      for (int c = 0; c < 8; ++c) pre[c] = ap[c] ? 0xFFFFu : 0u;
    }
  };

  loadRegs(j0);
  for (int c = 0; c < NC; ++c) {
    __syncthreads();
    {
      union { uint16_t u[8]; s16x8 s; } pk;
#pragma unroll
      for (int t = 0; t < 8; ++t) pk.u[t] = pre[t];
      *(s16x8*)&Msk[strow][stcol] = pk.s;
    }
    __syncthreads();
    if (c + 1 < NC) loadRegs(j0 + (c + 1) * 256);

    const int jb = j0 + c * 256;
    // one-step-ahead register prefetch of XT B-frags
    s16x8 nbx0 = *(const s16x8*)(x0 + jb + qd * 8);
    s16x8 nbx1 = *(const s16x8*)(x1 + jb + qd * 8);
#pragma unroll
    for (int st = 0; st < 8; ++st) {
      const s16x8 bx0 = nbx0, bx1 = nbx1;
      const int jq = st * 32 + qd * 8;
      if (st < 7) {
        nbx0 = *(const s16x8*)(x0 + jb + jq + 32);
        nbx1 = *(const s16x8*)(x1 + jb + jq + 32);
      }
      const f32x4 s0 = *(const f32x4*)(sS + jb + jq);
      const f32x4 s1 = *(const f32x4*)(sS + jb + jq + 4);
      const s16x8 mk = *(const s16x8*)&Msk[nl][jq];
      union { bf16x8 b; s16x8 s; } af;
#pragma unroll
      for (int cc = 0; cc < 8; ++cc) {
        const float v = tlog + ((cc < 4) ? s0[cc] : s1[cc - 4]);
        const float w = fmaxf(v, 0.2f * v);
        af.b[cc] = (__bf16)EXP2(w);
      }
      af.s = af.s & mk;  // masked P, exact zeros
      acc0 = __builtin_amdgcn_mfma_f32_16x16x32_bf16(af.s, bx0, acc0, 0, 0, 0);
      acc1 = __builtin_amdgcn_mfma_f32_16x16x32_bf16(af.s, bx1, acc1, 0, 0, 0);
      accD = __builtin_amdgcn_mfma_f32_16x16x32_bf16(af.s, ONES, accD, 0, 0, 0);
    }
  }

  // accD[r] = den for row qd*4+r (broadcast across cols) — no shuffles.
  if (JS == 1) {
#pragma unroll
    for (int r = 0; r < 4; ++r) {
      const int rw = qd * 4 + r;
      const float inv = 1.0f / accD[r];
      out[(size_t)(i0 + rw) * HF + h * 32 + nl] = acc0[r] * inv;
      out[(size_t)(i0 + rw) * HF + h * 32 + 16 + nl] = acc1[r] * inv;
    }
  } else {
    const size_t pb = (((size_t)js * 256 + tile) * HH + h) * 2;
    union { __bf16 b; uint16_t u; } cv;
#pragma unroll
    for (int r = 0; r < 4; ++r) {
      const int rw = qd * 4 + r;
      cv.b = (__bf16)acc0[r];
      pnum[(pb * 16 + rw) * 16 + nl] = cv.u;
      cv.b = (__bf16)acc1[r];
      pnum[((pb + 1) * 16 + rw) * 16 + nl] = cv.u;
    }
    if (nl == 0) {
#pragma unroll
      for (int r = 0; r < 4; ++r)
        pden[((size_t)js * 256 + tile) * 128 + h * 16 + qd * 4 + r] = accD[r];
    }
  }
}

// ---------------------------------------------------------------------------
__global__ __launch_bounds__(256) void k_reduce(
    const uint16_t* __restrict__ pnum, const float* __restrict__ pden,
    float* __restrict__ out, int JS) {
  const int gid = blockIdx.x * 256 + threadIdx.x;
  const int i = gid >> 8, col = gid & 255;
  const int tile = i >> 4, r = i & 15;
  const int h = col >> 5, ct = (col >> 4) & 1, cc = col & 15;
  float num = 0.f, den = 0.f;
  for (int js = 0; js < JS; ++js) {
    union { uint16_t u; __bf16 b; } cv;
    cv.u = pnum[(((((size_t)js * 256 + tile) * 8 + h) * 2 + ct) * 16 + r) * 16 + cc];
    num += (float)cv.b;
    den += pden[((size_t)js * 256 + tile) * 128 + h * 16 + r];
  }
  out[gid] = num / den;
}

// ---------------------------------------------------------------------------
extern "C" void kernel_launch(void* const* d_in, const int* in_sizes, int n_in,
                              void* d_out, int out_size, void* d_ws, size_t ws_size,
                              hipStream_t stream) {
  const float* node = (const float*)d_in[0];
  const void* adj = d_in[1];
  const float* Wm = (const float*)d_in[2];
  const float* avec = (const float*)d_in[3];
  float* out = (float*)d_out;

  uint8_t* ws = (uint8_t*)d_ws;
  uint16_t* XT = (uint16_t*)ws;                        // 2 MB
  float* sSrcT = (float*)(ws + 0x200000);              // 128 KB
  float* sTgtT = (float*)(ws + 0x220000);              // 128 KB
  int* flag = (int*)(ws + 0x240000);                   // 4 B (pad 1 KB)
  const size_t base = 0x240400;
  int JS = 1;
  if (ws_size >= base + 4 * (2097152ull + 131072ull)) JS = 4;
  else if (ws_size >= base + 2 * (2097152ull + 131072ull)) JS = 2;
  uint16_t* pnum = (uint16_t*)(ws + base);
  float* pden = (float*)(ws + base + (size_t)JS * 2097152ull);

  hipLaunchKernelGGL(k_prep, dim3(64, 4), dim3(256), 0, stream,
                     node, Wm, avec, adj, XT, sSrcT, sTgtT, flag);
  hipLaunchKernelGGL(k_attn, dim3(256, JS), dim3(512), 0, stream,
                     adj, flag, XT, sSrcT, sTgtT, pnum, pden, out);
  if (JS > 1)
    hipLaunchKernelGGL(k_reduce, dim3(4096), dim3(256), 0, stream,
                       pnum, pden, out, JS);
}

// Round 5
// 190.889 us; speedup vs baseline: 1.4048x; 1.0091x over previous
//
#include <hip/hip_runtime.h>
#include <hip/hip_bf16.h>
#include <stdint.h>

#define NN 4096
#define KIN 512
#define HH 8
#define HF 256
#define LOG2E 1.4426950408889634f

typedef float f32x4 __attribute__((ext_vector_type(4)));
typedef short s16x8 __attribute__((ext_vector_type(8)));
typedef __bf16 bf16x8 __attribute__((ext_vector_type(8)));
typedef unsigned int u32x4 __attribute__((ext_vector_type(4)));

#if defined(__has_builtin)
#if __has_builtin(__builtin_amdgcn_exp2f)
#define EXP2(x) __builtin_amdgcn_exp2f(x)
#else
#define EXP2(x) exp2f(x)
#endif
#else
#define EXP2(x) exp2f(x)
#endif

// ---------------------------------------------------------------------------
// k_prep: x = node@W via bf16 MFMA (64x64 tiles). Emits XT (bf16 [256][4096],
// coalesced via LDS transpose), sSrcT/sTgtT ([8][4096], log2-domain), flag.
// ---------------------------------------------------------------------------
__global__ __launch_bounds__(256) void k_prep(
    const float* __restrict__ node, const float* __restrict__ Wm,
    const float* __restrict__ avec, const void* __restrict__ adjv,
    uint16_t* __restrict__ XT, float* __restrict__ sSrcT,
    float* __restrict__ sTgtT, int* __restrict__ flag) {
  if (blockIdx.x == 0 && blockIdx.y == 0 && threadIdx.x == 0) {
    const uint32_t* aw = (const uint32_t*)adjv;
    const uint32_t w0 = aw[0];
    int f;
    if (w0 == 0x3F800000u) f = 2;                 // fp32 0/1
    else if ((w0 & 0xFFFFu) == 0x3F80u) f = 3;    // bf16 0/1
    else {
      int alli = 1;
      for (int k = 0; k < 64; ++k)
        if (aw[k] > 1u) { alli = 0; break; }
      f = alli ? 1 : 0;                           // int32 : uint8
    }
    *flag = f;
  }

  __shared__ __bf16 Ald[64][40];
  __shared__ __bf16 Bld[64][40];
  __shared__ __bf16 Cs[64][72];
  const int tid = threadIdx.x;
  const int wv = tid >> 6, ln = tid & 63, nl = ln & 15, qd = ln >> 4;
  const int row0 = blockIdx.x * 64, col0 = blockIdx.y * 64;
  const int rA = tid >> 2, kA = (tid & 3) * 8;
  const int kB = tid >> 3, cB = (tid & 7) * 8;

  f32x4 acc[4] = {{0,0,0,0},{0,0,0,0},{0,0,0,0},{0,0,0,0}};
  float4 a0, a1, b0, b1;

  auto ldg = [&](int k0) {
    a0 = *(const float4*)(node + (size_t)(row0 + rA) * KIN + k0 + kA);
    a1 = *(const float4*)(node + (size_t)(row0 + rA) * KIN + k0 + kA + 4);
    b0 = *(const float4*)(Wm + (size_t)(k0 + kB) * HF + col0 + cB);
    b1 = *(const float4*)(Wm + (size_t)(k0 + kB) * HF + col0 + cB + 4);
  };

  ldg(0);
  for (int k0 = 0; k0 < KIN; k0 += 32) {
    __syncthreads();
    {
      union { bf16x8 v; s16x8 s; } pk;
      pk.v[0] = (__bf16)a0.x; pk.v[1] = (__bf16)a0.y;
      pk.v[2] = (__bf16)a0.z; pk.v[3] = (__bf16)a0.w;
      pk.v[4] = (__bf16)a1.x; pk.v[5] = (__bf16)a1.y;
      pk.v[6] = (__bf16)a1.z; pk.v[7] = (__bf16)a1.w;
      *(s16x8*)&Ald[rA][kA] = pk.s;
      Bld[cB + 0][kB] = (__bf16)b0.x;
      Bld[cB + 1][kB] = (__bf16)b0.y;
      Bld[cB + 2][kB] = (__bf16)b0.z;
      Bld[cB + 3][kB] = (__bf16)b0.w;
      Bld[cB + 4][kB] = (__bf16)b1.x;
      Bld[cB + 5][kB] = (__bf16)b1.y;
      Bld[cB + 6][kB] = (__bf16)b1.z;
      Bld[cB + 7][kB] = (__bf16)b1.w;
    }
    __syncthreads();
    if (k0 + 32 < KIN) ldg(k0 + 32);
    const s16x8 af = *(const s16x8*)&Ald[wv * 16 + nl][qd * 8];
#pragma unroll
    for (int ct = 0; ct < 4; ++ct) {
      const s16x8 bfr = *(const s16x8*)&Bld[ct * 16 + nl][qd * 8];
      acc[ct] = __builtin_amdgcn_mfma_f32_16x16x32_bf16(af, bfr, acc[ct], 0, 0, 0);
    }
  }

#pragma unroll
  for (int ct = 0; ct < 4; ++ct)
#pragma unroll
    for (int r = 0; r < 4; ++r)
      Cs[ct * 16 + nl][wv * 16 + qd * 4 + r] = (__bf16)acc[ct][r];
  __syncthreads();
  {
    const int xr = tid >> 2;
#pragma unroll
    for (int sseg = 0; sseg < 2; ++sseg) {
      const int sc = ((tid & 3) * 2 + sseg) * 8;
      *(s16x8*)(XT + (size_t)(col0 + xr) * NN + row0 + sc) =
          *(const s16x8*)&Cs[xr][sc];
    }
  }

  const float as0 = avec[nl] * LOG2E, as1 = avec[16 + nl] * LOG2E;
  const float at0 = avec[32 + nl] * LOG2E, at1 = avec[48 + nl] * LOG2E;
#pragma unroll
  for (int hp = 0; hp < 2; ++hp) {
    float ps[4], pt[4];
#pragma unroll
    for (int r = 0; r < 4; ++r) {
      ps[r] = acc[2 * hp][r] * as0 + acc[2 * hp + 1][r] * as1;
      pt[r] = acc[2 * hp][r] * at0 + acc[2 * hp + 1][r] * at1;
    }
#pragma unroll
    for (int m = 1; m <= 8; m <<= 1)
#pragma unroll
      for (int r = 0; r < 4; ++r) {
        ps[r] += __shfl_xor(ps[r], m);
        pt[r] += __shfl_xor(pt[r], m);
      }
    if (nl == 0) {
      const int h = blockIdx.y * 2 + hp;
#pragma unroll
      for (int r = 0; r < 4; ++r) {
        sSrcT[h * NN + row0 + wv * 16 + qd * 4 + r] = ps[r];
        sTgtT[h * NN + row0 + wv * 16 + qd * 4 + r] = pt[r];
      }
    }
  }
}

// ---------------------------------------------------------------------------
// k_attn: block = 64 target rows x 8 heads (8 waves, M=64 per wave).
// Each step loads 2 XT B-frags shared by 4 A-frags (4x request amortization).
// Mask decoded bitwise-uniformly to 0xFFFF/0 u16 in LDS, applied as AND on
// packed bf16 P. den via ones-MFMA.
// ---------------------------------------------------------------------------
__global__ __launch_bounds__(512) void k_attn(
    const void* __restrict__ adjv, const int* __restrict__ flagp,
    const uint16_t* __restrict__ XT, const float* __restrict__ sSrcT,
    const float* __restrict__ sTgtT, uint16_t* __restrict__ pnum,
    float* __restrict__ pden, float* __restrict__ out) {
  __shared__ uint16_t Msk[64][264];  // stride 132 words == 4 mod 32: 2-way free
  const int tid = threadIdx.x;
  const int h = tid >> 6;
  const int ln = tid & 63, nl = ln & 15, qd = ln >> 4;
  const int tile = blockIdx.x, js = blockIdx.y, JS = gridDim.y;
  const int i0 = tile * 64;
  const int jlen = NN / JS, j0 = js * jlen, NC = jlen / 256;
  const int mode = *flagp;
  const int srow = tid >> 3, scb = (tid & 7) * 32;  // staging: row, col-base

  float tl[4];
#pragma unroll
  for (int ib = 0; ib < 4; ++ib)
    tl[ib] = sTgtT[h * NN + i0 + ib * 16 + nl];
  const float* sS = sSrcT + h * NN;
  const uint16_t* x0 = XT + (size_t)(h * 32 + nl) * NN;
  const uint16_t* x1 = x0 + (size_t)16 * NN;

  const short one_bf = (short)0x3F80;
  const s16x8 ONES = {one_bf, one_bf, one_bf, one_bf,
                      one_bf, one_bf, one_bf, one_bf};

  f32x4 acc0[4] = {{0,0,0,0},{0,0,0,0},{0,0,0,0},{0,0,0,0}};
  f32x4 acc1[4] = {{0,0,0,0},{0,0,0,0},{0,0,0,0},{0,0,0,0}};
  f32x4 accD[4] = {{0,0,0,0},{0,0,0,0},{0,0,0,0},{0,0,0,0}};

  union { uint16_t u[32]; s16x8 v[4]; } pre;

  // bitwise-nonzero test works for every mode's 0/1 encoding
  auto loadRegs = [&](int jbase) {
    const size_t eidx = (size_t)(i0 + srow) * NN + jbase + scb;
    if (mode == 0) {            // 1 B/elem
      const u32x4* p = (const u32x4*)((const uint8_t*)adjv + eidx);
#pragma unroll
      for (int k = 0; k < 2; ++k) {
        const u32x4 w = __builtin_nontemporal_load(&p[k]);
#pragma unroll
        for (int q = 0; q < 4; ++q)
#pragma unroll
          for (int b = 0; b < 4; ++b)
            pre.u[k * 16 + q * 4 + b] =
                ((w[q] >> (8 * b)) & 0xFFu) ? 0xFFFFu : 0u;
      }
    } else if (mode == 3) {     // 2 B/elem
      const u32x4* p = (const u32x4*)((const uint16_t*)adjv + eidx);
#pragma unroll
      for (int k = 0; k < 4; ++k) {
        const u32x4 w = __builtin_nontemporal_load(&p[k]);
#pragma unroll
        for (int q = 0; q < 4; ++q) {
          pre.u[k * 8 + q * 2 + 0] = (w[q] & 0xFFFFu) ? 0xFFFFu : 0u;
          pre.u[k * 8 + q * 2 + 1] = (w[q] >> 16) ? 0xFFFFu : 0u;
        }
      }
    } else {                    // 4 B/elem (int32 or fp32)
      const u32x4* p = (const u32x4*)((const uint32_t*)adjv + eidx);
#pragma unroll
      for (int k = 0; k < 8; ++k) {
        const u32x4 w = __builtin_nontemporal_load(&p[k]);
#pragma unroll
        for (int q = 0; q < 4; ++q)
          pre.u[k * 4 + q] = w[q] ? 0xFFFFu : 0u;
      }
    }
  };

  loadRegs(j0);
  for (int c = 0; c < NC; ++c) {
    __syncthreads();
#pragma unroll
    for (int seg = 0; seg < 4; ++seg)
      *(s16x8*)&Msk[srow][scb + seg * 8] = pre.v[seg];
    __syncthreads();
    if (c + 1 < NC) loadRegs(j0 + (c + 1) * 256);

    const int jb = j0 + c * 256;
    s16x8 nbx0 = *(const s16x8*)(x0 + jb + qd * 8);
    s16x8 nbx1 = *(const s16x8*)(x1 + jb + qd * 8);
#pragma unroll
    for (int st = 0; st < 8; ++st) {
      const s16x8 bx0 = nbx0, bx1 = nbx1;
      const int jq = st * 32 + qd * 8;
      if (st < 7) {
        nbx0 = *(const s16x8*)(x0 + jb + jq + 32);
        nbx1 = *(const s16x8*)(x1 + jb + jq + 32);
      }
      const f32x4 s0 = *(const f32x4*)(sS + jb + jq);
      const f32x4 s1 = *(const f32x4*)(sS + jb + jq + 4);
      const float sv[8] = {s0[0], s0[1], s0[2], s0[3],
                           s1[0], s1[1], s1[2], s1[3]};
#pragma unroll
      for (int ib = 0; ib < 4; ++ib) {
        const s16x8 mk = *(const s16x8*)&Msk[ib * 16 + nl][jq];
        union { bf16x8 b; s16x8 s; } af;
#pragma unroll
        for (int cc = 0; cc < 8; ++cc) {
          const float v = tl[ib] + sv[cc];
          const float w = fmaxf(v, 0.2f * v);
          af.b[cc] = (__bf16)EXP2(w);
        }
        af.s = af.s & mk;
        acc0[ib] = __builtin_amdgcn_mfma_f32_16x16x32_bf16(af.s, bx0, acc0[ib], 0, 0, 0);
        acc1[ib] = __builtin_amdgcn_mfma_f32_16x16x32_bf16(af.s, bx1, acc1[ib], 0, 0, 0);
        accD[ib] = __builtin_amdgcn_mfma_f32_16x16x32_bf16(af.s, ONES, accD[ib], 0, 0, 0);
      }
    }
  }

  if (JS == 1) {
#pragma unroll
    for (int ib = 0; ib < 4; ++ib)
#pragma unroll
      for (int r = 0; r < 4; ++r) {
        const int rw = ib * 16 + qd * 4 + r;
        const float inv = 1.0f / accD[ib][r];
        out[(size_t)(i0 + rw) * HF + h * 32 + nl] = acc0[ib][r] * inv;
        out[(size_t)(i0 + rw) * HF + h * 32 + 16 + nl] = acc1[ib][r] * inv;
      }
  } else {
    union { __bf16 b; uint16_t u; } cv;
#pragma unroll
    for (int ib = 0; ib < 4; ++ib) {
      const int t16 = tile * 4 + ib;
      const size_t pb = (((size_t)js * 256 + t16) * HH + h) * 2;
#pragma unroll
      for (int r = 0; r < 4; ++r) {
        const int rw = qd * 4 + r;
        cv.b = (__bf16)acc0[ib][r];
        pnum[(pb * 16 + rw) * 16 + nl] = cv.u;
        cv.b = (__bf16)acc1[ib][r];
        pnum[((pb + 1) * 16 + rw) * 16 + nl] = cv.u;
      }
      if (nl == 0) {
#pragma unroll
        for (int r = 0; r < 4; ++r)
          pden[((size_t)js * 256 + t16) * 128 + h * 16 + qd * 4 + r] =
              accD[ib][r];
      }
    }
  }
}

// ---------------------------------------------------------------------------
__global__ __launch_bounds__(256) void k_reduce(
    const uint16_t* __restrict__ pnum, const float* __restrict__ pden,
    float* __restrict__ out, int JS) {
  const int gid = blockIdx.x * 256 + threadIdx.x;
  const int i = gid >> 8, col = gid & 255;
  const int tile = i >> 4, r = i & 15;
  const int h = col >> 5, ct = (col >> 4) & 1, cc = col & 15;
  float num = 0.f, den = 0.f;
  for (int js = 0; js < JS; ++js) {
    union { uint16_t u; __bf16 b; } cv;
    cv.u = pnum[(((((size_t)js * 256 + tile) * 8 + h) * 2 + ct) * 16 + r) * 16 + cc];
    num += (float)cv.b;
    den += pden[((size_t)js * 256 + tile) * 128 + h * 16 + r];
  }
  out[gid] = num / den;
}

// ---------------------------------------------------------------------------
extern "C" void kernel_launch(void* const* d_in, const int* in_sizes, int n_in,
                              void* d_out, int out_size, void* d_ws, size_t ws_size,
                              hipStream_t stream) {
  const float* node = (const float*)d_in[0];
  const void* adj = d_in[1];
  const float* Wm = (const float*)d_in[2];
  const float* avec = (const float*)d_in[3];
  float* out = (float*)d_out;

  uint8_t* ws = (uint8_t*)d_ws;
  uint16_t* XT = (uint16_t*)ws;                        // 2 MB
  float* sSrcT = (float*)(ws + 0x200000);              // 128 KB
  float* sTgtT = (float*)(ws + 0x220000);              // 128 KB
  int* flag = (int*)(ws + 0x240000);                   // 4 B (pad 1 KB)
  const size_t base = 0x240400;
  const size_t per = 2097152ull + 131072ull;           // pnum + pden per slice
  int JS = 1;
  if (ws_size >= base + 8 * per) JS = 8;
  else if (ws_size >= base + 4 * per) JS = 4;
  else if (ws_size >= base + 2 * per) JS = 2;
  uint16_t* pnum = (uint16_t*)(ws + base);
  float* pden = (float*)(ws + base + (size_t)JS * 2097152ull);

  hipLaunchKernelGGL(k_prep, dim3(64, 4), dim3(256), 0, stream,
                     node, Wm, avec, adj, XT, sSrcT, sTgtT, flag);
  hipLaunchKernelGGL(k_attn, dim3(64, JS), dim3(512), 0, stream,
                     adj, flag, XT, sSrcT, sTgtT, pnum, pden, out);
  if (JS > 1)
    hipLaunchKernelGGL(k_reduce, dim3(4096), dim3(256), 0, stream,
                       pnum, pden, out, JS);
}